// Round 5
// baseline (711.082 us; speedup 1.0000x reference)
//
#include <hip/hip_runtime.h>
#include <math.h>

#define EPSF 1e-6f

__device__ __constant__ int DISK[37] = {
    2, 3, 4,
    8, 9, 10, 11, 12,
    14, 15, 16, 17, 18, 19, 20,
    21, 22, 23, 24, 25, 26, 27,
    28, 29, 30, 31, 32, 33, 34,
    36, 37, 38, 39, 40,
    44, 45, 46};

// ---------------------------------------------------------------------------
// g[n, d, rm] = sum_c Wc[d, c, rm] * x[n, c];  Wc = W_conv * exp(i*phase)
// g stored interleaved float2, layout [n][d*18+rm]
// ---------------------------------------------------------------------------
__global__ __launch_bounds__(256) void g_kernel(
    const float* __restrict__ x_re, const float* __restrict__ x_im,
    const float* __restrict__ W_conv, const float* __restrict__ phase,
    float2* __restrict__ g2, int N) {
  __shared__ float wc_re[1152];
  __shared__ float wc_im[1152];
  int t = threadIdx.x;
  for (int i = t; i < 1152; i += 256) {
    int dc = i / 18;
    float w = W_conv[i];
    float ph = phase[dc];
    wc_re[i] = w * cosf(ph);
    wc_im[i] = w * sinf(ph);
  }
  __syncthreads();
  int gid = blockIdx.x * 256 + t;
  int total = N * 144;
  if (gid >= total) return;
  int n = gid / 144;
  int q = gid - n * 144;  // d*18 + rm
  int d = q / 18;
  int rm = q - d * 18;
  const float* xr = x_re + n * 8;
  const float* xi = x_im + n * 8;
  float ar = 0.f, ai = 0.f;
#pragma unroll
  for (int c = 0; c < 8; ++c) {
    float wr = wc_re[(d * 8 + c) * 18 + rm];
    float wi = wc_im[(d * 8 + c) * 18 + rm];
    float vr = xr[c], vi = xi[c];
    ar += wr * vr - wi * vi;
    ai += wr * vi + wi * vr;
  }
  g2[gid] = make_float2(ar, ai);
}

// ---------------------------------------------------------------------------
// CSR build: count both dst (cnt) and src (scnt) degrees in one pass
// ---------------------------------------------------------------------------
__global__ __launch_bounds__(256) void count_kernel(const int* __restrict__ edges,
                                                    int* __restrict__ cnt,
                                                    int* __restrict__ scnt, int E) {
  int e = blockIdx.x * 256 + threadIdx.x;
  if (e >= E) return;
  atomicAdd(&cnt[edges[2 * e + 1]], 1);
  atomicAdd(&scnt[edges[2 * e]], 1);
}

// Single-block dual exclusive scan: cnt->offs,cur and scnt->soffs,scur
__global__ __launch_bounds__(1024) void scan_dual_kernel(
    const int* __restrict__ cnt, int* __restrict__ offs, int* __restrict__ cur,
    const int* __restrict__ scnt, int* __restrict__ soffs, int* __restrict__ scur,
    int N) {
  __shared__ int sums[1024];
  int t = threadIdx.x;
  int per = (N + 1023) / 1024;
  for (int pass = 0; pass < 2; ++pass) {
    const int* c = pass ? scnt : cnt;
    int* o = pass ? soffs : offs;
    int* u = pass ? scur : cur;
    int base = t * per;
    int s = 0;
    for (int i = 0; i < per; ++i) {
      int idx = base + i;
      if (idx < N) s += c[idx];
    }
    sums[t] = s;
    __syncthreads();
    for (int d = 1; d < 1024; d <<= 1) {
      int v = (t >= d) ? sums[t - d] : 0;
      __syncthreads();
      sums[t] += v;
      __syncthreads();
    }
    int run = (t == 0) ? 0 : sums[t - 1];
    for (int i = 0; i < per; ++i) {
      int idx = base + i;
      if (idx < N) {
        int cc = c[idx];
        o[idx] = run;
        u[idx] = run;
        run += cc;
      }
    }
    if (t == 1023) o[N] = sums[1023];
    __syncthreads();
  }
}

// fill both CSRs; sdpos links src-slot -> dst-slot so conv can write ye
// directly into the dst-CSR slot.
__global__ __launch_bounds__(256) void fill_kernel(
    const int* __restrict__ edges, int* __restrict__ cur, int* __restrict__ scur,
    const float* __restrict__ wxp_re, const float* __restrict__ wxp_im,
    const float* __restrict__ ln_re, const float* __restrict__ ln_im,
    int* __restrict__ src_l, float4* __restrict__ wln,
    int* __restrict__ selist, int* __restrict__ sdpos, int E) {
  int e = blockIdx.x * 256 + threadIdx.x;
  if (e >= E) return;
  int src = edges[2 * e];
  int dst = edges[2 * e + 1];
  int pos = atomicAdd(&cur[dst], 1);
  src_l[pos] = src;
  wln[pos] = make_float4(wxp_re[e], wxp_im[e], ln_re[e], ln_im[e]);
  int pos2 = atomicAdd(&scur[src], 1);
  selist[pos2] = e;
  sdpos[pos2] = pos;
}

// ---------------------------------------------------------------------------
// Edge conv in src-grouped order: wave per src node, g-row held in VGPRs,
// reused for all outgoing edges. Writes ye (8 complex) to dst-CSR slot.
// lane = es*8 + d.
// ---------------------------------------------------------------------------
__global__ __launch_bounds__(256, 4) void conv_src_kernel(
    const int* __restrict__ soffs, const int* __restrict__ selist,
    const int* __restrict__ sdpos,
    const float* __restrict__ sten_re, const float* __restrict__ sten_im,
    const float2* __restrict__ g2, float2* __restrict__ yebuf, int N) {
  int t = threadIdx.x;
  int m = blockIdx.x * 4 + (t >> 6);
  if (m >= N) return;
  int lane = t & 63;
  int es = lane >> 3;
  int d = lane & 7;
  float gr[18], gi[18];
  const float4* gq = (const float4*)(g2 + (size_t)m * 144 + d * 18);
#pragma unroll
  for (int p = 0; p < 9; ++p) {
    float4 v = gq[p];
    gr[2 * p] = v.x; gi[2 * p] = v.y;
    gr[2 * p + 1] = v.z; gi[2 * p + 1] = v.w;
  }
  int beg = soffs[m], end = soffs[m + 1];
  for (int i = beg + es; i < end; i += 8) {
    int e = selist[i];
    int ds = sdpos[i];
    const float2* pre = (const float2*)(sten_re + (size_t)e * 18);
    const float2* pim = (const float2*)(sten_im + (size_t)e * 18);
    float ar = 0.f, ai = 0.f;
#pragma unroll
    for (int p = 0; p < 9; ++p) {
      float2 a = pre[p];
      float2 b = pim[p];
      int rm = 2 * p;
      ar += a.x * gr[rm] - b.x * gi[rm];
      ai += a.x * gi[rm] + b.x * gr[rm];
      ar += a.y * gr[rm + 1] - b.y * gi[rm + 1];
      ai += a.y * gi[rm + 1] + b.y * gr[rm + 1];
    }
    yebuf[(size_t)ds * 8 + d] = make_float2(ar, ai);
  }
}

// ---------------------------------------------------------------------------
// Reduce ye over each node's contiguous dst-slot range + nonlinearity -> y
// ---------------------------------------------------------------------------
__global__ __launch_bounds__(256, 4) void ye_reduce_kernel(
    const int* __restrict__ offs, const float2* __restrict__ yebuf,
    const float* __restrict__ b_nl, float* __restrict__ y, int N) {
  int t = threadIdx.x;
  int n = blockIdx.x * 4 + (t >> 6);
  if (n >= N) return;
  int lane = t & 63;
  int es = lane >> 3;
  int d = lane & 7;
  int beg = offs[n], end = offs[n + 1];
  float ar = 0.f, ai = 0.f;
  for (int i = beg + es; i < end; i += 8) {
    float2 v = yebuf[(size_t)i * 8 + d];
    ar += v.x;
    ai += v.y;
  }
  ar += __shfl_xor(ar, 8);
  ai += __shfl_xor(ai, 8);
  ar += __shfl_xor(ar, 16);
  ai += __shfl_xor(ai, 16);
  ar += __shfl_xor(ar, 32);
  ai += __shfl_xor(ai, 32);
  if (lane < 8) {
    float mag = sqrtf(ar * ar + ai * ai);
    float s = fmaxf(mag + b_nl[d], 0.f) / (mag + EPSF);
    y[(size_t)n * 16 + 2 * d] = ar * s;
    y[(size_t)n * 16 + 2 * d + 1] = ai * s;
  }
}

// ---------------------------------------------------------------------------
// Histogram: 8 nodes/block, 32 lanes/node, d-major padded LDS layout.
// Writes desc[n][296] (disk-gathered, (d,k) order) to global.
// ---------------------------------------------------------------------------
__global__ __launch_bounds__(256, 4) void hist_kernel(
    const int* __restrict__ offs, const int* __restrict__ src_l,
    const float4* __restrict__ wln, const float* __restrict__ y,
    float* __restrict__ desc_g, int N) {
  __shared__ float hl[8 * 417];
  int t = threadIdx.x;
  int n0 = blockIdx.x * 8;
  for (int i = t; i < 8 * 417; i += 256) hl[i] = 0.f;
  __syncthreads();

  int v = t >> 5;
  int l = t & 31;
  int n = n0 + v;
  if (n < N) {
    int beg = offs[n], end = offs[n + 1];
    float* hv = hl + v * 417;
    for (int i = beg + l; i < end; i += 32) {
      int src = src_l[i];
      float4 w4 = wln[i];
      float wr = w4.x, wi = w4.y, lr = w4.z, li = w4.w;
      const float4* yp = (const float4*)(y + (size_t)src * 16);
#pragma unroll
      for (int p = 0; p < 4; ++p) {
        float4 yv = yp[p];
#pragma unroll
        for (int h = 0; h < 2; ++h) {
          int d = 2 * p + h;
          float yr = h ? yv.z : yv.x;
          float yi = h ? yv.w : yv.y;
          float fr = yr * wr - yi * wi;
          float fi = yr * wi + yi * wr;
          float fm = sqrtf(fr * fr + fi * fi);
          float inv = 1.f / (fm + EPSF);
          float cr = (lr * fr + li * fi) * inv;
          float ci = (li * fr - lr * fi) * inv;
          float gx = cr * 3.f + 3.f;
          float gy = ci * 3.f + 3.f;
          float x0f = floorf(gx), y0f = floorf(gy);
          float wx = gx - x0f, wy = gy - y0f;
          int x0i = min(max((int)x0f, 0), 6);
          int x1i = min(x0i + 1, 6);
          int y0i = min(max((int)y0f, 0), 6);
          int y1i = min(y0i + 1, 6);
          float* hd = hv + d * 52;
          atomicAdd(hd + x0i * 7 + y0i, fm * (1.f - wx) * (1.f - wy));
          atomicAdd(hd + x1i * 7 + y0i, fm * wx * (1.f - wy));
          atomicAdd(hd + x0i * 7 + y1i, fm * (1.f - wx) * wy);
          atomicAdd(hd + x1i * 7 + y1i, fm * wx * wy);
        }
      }
    }
  }
  __syncthreads();

  for (int i = t; i < 8 * 296; i += 256) {
    int vv = i / 296;
    int q = i - vv * 296;
    int d = q / 37;
    int k = q - d * 37;
    int nn = n0 + vv;
    if (nn < N) desc_g[(size_t)nn * 296 + q] = hl[vv * 417 + d * 52 + DISK[k]];
  }
}

// ---------------------------------------------------------------------------
// MLP as register-blocked fp32 GEMM. 32 nodes/block, 256 threads.
// Layer1: each thread computes 4 nodes x 4 j (j = jt+32*jj). K chunks of 40
// staged in LDS: bufA [32][40] node-major (broadcast reads), bufB k-major
// [kk][128] stride 132 (conflict-free per-lane j reads, coalesced global
// staging). Layers 2/3: A read from h1s/h2s, W2/W3 staged k-major stride 66.
// ---------------------------------------------------------------------------
__global__ __launch_bounds__(256, 3) void mlp_kernel(
    const float* __restrict__ desc_g,
    const float* __restrict__ x_re, const float* __restrict__ x_im,
    const float* __restrict__ W1, const float* __restrict__ b1,
    const float* __restrict__ W2, const float* __restrict__ b2,
    const float* __restrict__ W3, const float* __restrict__ b3,
    const float* __restrict__ Wres, const float* __restrict__ bres,
    float* __restrict__ out, int N) {
  __shared__ float bufA[32 * 40];
  __shared__ float bufB[40 * 132];  // >= 64*66 too
  __shared__ float h1s[32][128];
  __shared__ float h2s[32][64];
  __shared__ float rmag[32][8];
  int t = threadIdx.x;
  int n0blk = blockIdx.x * 32;
  int jt = t & 31;
  int mt = t >> 5;  // 0..7
  int nb = mt * 4;

  // rmag
  {
    int v = t >> 3, c = t & 7;  // covers 32 nodes x 8 ch
    int n = n0blk + v;
    if (n < N) {
      float xr = x_re[n * 8 + c], xi = x_im[n * 8 + c];
      rmag[v][c] = sqrtf(xr * xr + xi * xi + EPSF);
    } else {
      rmag[v][c] = 0.f;
    }
  }

  // ---------------- Layer 1: [32 x 296] @ [296 x 128] ----------------
  float acc[4][4];
#pragma unroll
  for (int jj = 0; jj < 4; ++jj) {
    float bb = b1[jt + 32 * jj];
#pragma unroll
    for (int i = 0; i < 4; ++i) acc[i][jj] = bb;
  }
  for (int k0 = 0; k0 < 296; k0 += 40) {
    int kc = min(40, 296 - k0);
    int kc4 = kc >> 2;
    // stage A: desc chunk [32][kc], float4
    for (int i = t; i < 32 * kc4; i += 256) {
      int r = i / kc4, c4 = (i - r * kc4) * 4;
      int n = n0blk + r;
      float4 v = (n < N) ? *(const float4*)&desc_g[(size_t)n * 296 + k0 + c4]
                         : make_float4(0.f, 0.f, 0.f, 0.f);
      *(float4*)&bufA[r * 40 + c4] = v;
    }
    // stage B k-major: bufB[kk*132 + j]
    for (int i = t; i < 128 * kc4; i += 256) {
      int r = i / kc4, c4 = (i - r * kc4) * 4;
      float4 w = *(const float4*)&W1[(size_t)r * 296 + k0 + c4];
      bufB[(c4 + 0) * 132 + r] = w.x;
      bufB[(c4 + 1) * 132 + r] = w.y;
      bufB[(c4 + 2) * 132 + r] = w.z;
      bufB[(c4 + 3) * 132 + r] = w.w;
    }
    __syncthreads();
    for (int kk = 0; kk < kc; kk += 4) {
      float4 a[4];
#pragma unroll
      for (int i = 0; i < 4; ++i) a[i] = *(const float4*)&bufA[(nb + i) * 40 + kk];
#pragma unroll
      for (int q = 0; q < 4; ++q) {
        float bv[4];
#pragma unroll
        for (int jj = 0; jj < 4; ++jj) bv[jj] = bufB[(kk + q) * 132 + jt + 32 * jj];
#pragma unroll
        for (int i = 0; i < 4; ++i) {
          float av = (q == 0) ? a[i].x : (q == 1) ? a[i].y : (q == 2) ? a[i].z : a[i].w;
#pragma unroll
          for (int jj = 0; jj < 4; ++jj) acc[i][jj] += av * bv[jj];
        }
      }
    }
    __syncthreads();
  }
#pragma unroll
  for (int i = 0; i < 4; ++i)
#pragma unroll
    for (int jj = 0; jj < 4; ++jj)
      h1s[nb + i][jt + 32 * jj] = fmaxf(acc[i][jj], 0.f);

  // ---------------- Layer 2: [32 x 128] @ [128 x 64] ----------------
  float acc2[4][2];
#pragma unroll
  for (int jj = 0; jj < 2; ++jj) {
    float bb = b2[jt + 32 * jj];
#pragma unroll
    for (int i = 0; i < 4; ++i) acc2[i][jj] = bb;
  }
  for (int k0 = 0; k0 < 128; k0 += 64) {
    // stage W2 chunk k-major: bufB[kk*66 + j], 64 rows x 64 k
    for (int i = t; i < 64 * 16; i += 256) {
      int r = i >> 4, c4 = (i & 15) * 4;
      float4 w = *(const float4*)&W2[(size_t)r * 128 + k0 + c4];
      bufB[(c4 + 0) * 66 + r] = w.x;
      bufB[(c4 + 1) * 66 + r] = w.y;
      bufB[(c4 + 2) * 66 + r] = w.z;
      bufB[(c4 + 3) * 66 + r] = w.w;
    }
    __syncthreads();
    for (int kk = 0; kk < 64; kk += 4) {
      float4 a[4];
#pragma unroll
      for (int i = 0; i < 4; ++i) a[i] = *(const float4*)&h1s[nb + i][k0 + kk];
#pragma unroll
      for (int q = 0; q < 4; ++q) {
        float bv[2];
#pragma unroll
        for (int jj = 0; jj < 2; ++jj) bv[jj] = bufB[(kk + q) * 66 + jt + 32 * jj];
#pragma unroll
        for (int i = 0; i < 4; ++i) {
          float av = (q == 0) ? a[i].x : (q == 1) ? a[i].y : (q == 2) ? a[i].z : a[i].w;
#pragma unroll
          for (int jj = 0; jj < 2; ++jj) acc2[i][jj] += av * bv[jj];
        }
      }
    }
    __syncthreads();
  }
#pragma unroll
  for (int i = 0; i < 4; ++i)
#pragma unroll
    for (int jj = 0; jj < 2; ++jj)
      h2s[nb + i][jt + 32 * jj] = fmaxf(acc2[i][jj], 0.f);

  // ---------------- Layer 3 + residual ----------------
  float acc3[4][2];
#pragma unroll
  for (int jj = 0; jj < 2; ++jj) {
    float bb = b3[jt + 32 * jj] + bres[jt + 32 * jj];
#pragma unroll
    for (int i = 0; i < 4; ++i) acc3[i][jj] = bb;
  }
  // stage W3 k-major: bufB[kk*66 + j]
  for (int i = t; i < 64 * 16; i += 256) {
    int r = i >> 4, c4 = (i & 15) * 4;
    float4 w = *(const float4*)&W3[(size_t)r * 64 + c4];
    bufB[(c4 + 0) * 66 + r] = w.x;
    bufB[(c4 + 1) * 66 + r] = w.y;
    bufB[(c4 + 2) * 66 + r] = w.z;
    bufB[(c4 + 3) * 66 + r] = w.w;
  }
  __syncthreads();
  for (int kk = 0; kk < 64; kk += 4) {
    float4 a[4];
#pragma unroll
    for (int i = 0; i < 4; ++i) a[i] = *(const float4*)&h2s[nb + i][kk];
#pragma unroll
    for (int q = 0; q < 4; ++q) {
      float bv[2];
#pragma unroll
      for (int jj = 0; jj < 2; ++jj) bv[jj] = bufB[(kk + q) * 66 + jt + 32 * jj];
#pragma unroll
      for (int i = 0; i < 4; ++i) {
        float av = (q == 0) ? a[i].x : (q == 1) ? a[i].y : (q == 2) ? a[i].z : a[i].w;
#pragma unroll
        for (int jj = 0; jj < 2; ++jj) acc3[i][jj] += av * bv[jj];
      }
    }
  }
  // residual
#pragma unroll
  for (int jj = 0; jj < 2; ++jj) {
    int j = jt + 32 * jj;
    float wrr[8];
    const float* wp = Wres + (size_t)j * 8;
#pragma unroll
    for (int c = 0; c < 8; ++c) wrr[c] = wp[c];
#pragma unroll
    for (int i = 0; i < 4; ++i) {
      float s = acc3[i][jj];
#pragma unroll
      for (int c = 0; c < 8; ++c) s += wrr[c] * rmag[nb + i][c];
      int n = n0blk + nb + i;
      if (n < N) out[(size_t)n * 64 + j] = s;
    }
  }
}

extern "C" void kernel_launch(void* const* d_in, const int* in_sizes, int n_in,
                              void* d_out, int out_size, void* d_ws, size_t ws_size,
                              hipStream_t stream) {
  (void)n_in; (void)out_size; (void)ws_size;
  const float* x_re = (const float*)d_in[0];
  const float* x_im = (const float*)d_in[1];
  const int* edges = (const int*)d_in[2];
  const float* sten_re = (const float*)d_in[3];
  const float* sten_im = (const float*)d_in[4];
  const float* ln_re = (const float*)d_in[5];
  const float* ln_im = (const float*)d_in[6];
  const float* wxp_re = (const float*)d_in[7];
  const float* wxp_im = (const float*)d_in[8];
  const float* W_conv = (const float*)d_in[9];
  const float* phase = (const float*)d_in[10];
  const float* b_nl = (const float*)d_in[11];
  const float* W1 = (const float*)d_in[12];
  const float* b1 = (const float*)d_in[13];
  const float* W2 = (const float*)d_in[14];
  const float* b2 = (const float*)d_in[15];
  const float* W3 = (const float*)d_in[16];
  const float* b3 = (const float*)d_in[17];
  const float* Wres = (const float*)d_in[18];
  const float* bres = (const float*)d_in[19];
  float* out = (float*)d_out;

  int N = in_sizes[0] / 8;
  int E = in_sizes[2] / 2;

  // workspace layout (16B-aligned blocks first)
  float* ws = (float*)d_ws;
  float4* wln = (float4*)ws;                          // E float4
  float* g2f = ws + (size_t)E * 4;                    // N*288 floats
  float2* g2 = (float2*)g2f;
  float* y = g2f + (size_t)N * 288;                   // N*16
  float* yebuf_f = y + (size_t)N * 16;                // E*16 floats; desc_g aliases
  float2* yebuf = (float2*)yebuf_f;
  float* desc_g = yebuf_f;                            // N*296 <= E*16; ye dead by then
  int* cnt = (int*)(yebuf_f + (size_t)E * 16);        // N
  int* offs = cnt + N;                                // N+1
  int* cur = offs + N + 1;                            // N
  int* scnt = cur + N;                                // N
  int* soffs = scnt + N;                              // N+1
  int* scur = soffs + N + 1;                          // N
  int* selist = scur + N;                             // E
  int* sdpos = selist + E;                            // E
  int* src_l = sdpos + E;                             // E

  hipMemsetAsync(cnt, 0, (size_t)N * sizeof(int), stream);
  hipMemsetAsync(scnt, 0, (size_t)N * sizeof(int), stream);

  g_kernel<<<(N * 144 + 255) / 256, 256, 0, stream>>>(x_re, x_im, W_conv, phase, g2, N);
  count_kernel<<<(E + 255) / 256, 256, 0, stream>>>(edges, cnt, scnt, E);
  scan_dual_kernel<<<1, 1024, 0, stream>>>(cnt, offs, cur, scnt, soffs, scur, N);
  fill_kernel<<<(E + 255) / 256, 256, 0, stream>>>(edges, cur, scur, wxp_re, wxp_im,
                                                   ln_re, ln_im, src_l, wln,
                                                   selist, sdpos, E);
  conv_src_kernel<<<(N + 3) / 4, 256, 0, stream>>>(soffs, selist, sdpos, sten_re,
                                                   sten_im, g2, yebuf, N);
  ye_reduce_kernel<<<(N + 3) / 4, 256, 0, stream>>>(offs, yebuf, b_nl, y, N);
  hist_kernel<<<(N + 7) / 8, 256, 0, stream>>>(offs, src_l, wln, y, desc_g, N);
  mlp_kernel<<<(N + 31) / 32, 256, 0, stream>>>(desc_g, x_re, x_im, W1, b1, W2, b2,
                                                W3, b3, Wres, bres, out, N);
}

// Round 6
// 619.740 us; speedup vs baseline: 1.1474x; 1.1474x over previous
//
#include <hip/hip_runtime.h>
#include <math.h>

#define EPSF 1e-6f

__device__ __constant__ int DISK[37] = {
    2, 3, 4,
    8, 9, 10, 11, 12,
    14, 15, 16, 17, 18, 19, 20,
    21, 22, 23, 24, 25, 26, 27,
    28, 29, 30, 31, 32, 33, 34,
    36, 37, 38, 39, 40,
    44, 45, 46};

// ---------------------------------------------------------------------------
// g[n, d, rm] = sum_c Wc[d, c, rm] * x[n, c];  Wc = W_conv * exp(i*phase)
// g stored interleaved float2, layout [n][d*18+rm]
// ---------------------------------------------------------------------------
__global__ __launch_bounds__(256) void g_kernel(
    const float* __restrict__ x_re, const float* __restrict__ x_im,
    const float* __restrict__ W_conv, const float* __restrict__ phase,
    float2* __restrict__ g2, int N) {
  __shared__ float wc_re[1152];
  __shared__ float wc_im[1152];
  int t = threadIdx.x;
  for (int i = t; i < 1152; i += 256) {
    int dc = i / 18;
    float w = W_conv[i];
    float ph = phase[dc];
    wc_re[i] = w * cosf(ph);
    wc_im[i] = w * sinf(ph);
  }
  __syncthreads();
  int gid = blockIdx.x * 256 + t;
  int total = N * 144;
  if (gid >= total) return;
  int n = gid / 144;
  int q = gid - n * 144;  // d*18 + rm
  int d = q / 18;
  int rm = q - d * 18;
  const float* xr = x_re + n * 8;
  const float* xi = x_im + n * 8;
  float ar = 0.f, ai = 0.f;
#pragma unroll
  for (int c = 0; c < 8; ++c) {
    float wr = wc_re[(d * 8 + c) * 18 + rm];
    float wi = wc_im[(d * 8 + c) * 18 + rm];
    float vr = xr[c], vi = xi[c];
    ar += wr * vr - wi * vi;
    ai += wr * vi + wi * vr;
  }
  g2[gid] = make_float2(ar, ai);
}

// ---------------------------------------------------------------------------
// CSR build: count both dst (cnt) and src (scnt) degrees in one pass
// ---------------------------------------------------------------------------
__global__ __launch_bounds__(256) void count_kernel(const int* __restrict__ edges,
                                                    int* __restrict__ cnt,
                                                    int* __restrict__ scnt, int E) {
  int e = blockIdx.x * 256 + threadIdx.x;
  if (e >= E) return;
  atomicAdd(&cnt[edges[2 * e + 1]], 1);
  atomicAdd(&scnt[edges[2 * e]], 1);
}

// Single-block dual exclusive scan: cnt->offs,cur and scnt->soffs,scur
__global__ __launch_bounds__(1024) void scan_dual_kernel(
    const int* __restrict__ cnt, int* __restrict__ offs, int* __restrict__ cur,
    const int* __restrict__ scnt, int* __restrict__ soffs, int* __restrict__ scur,
    int N) {
  __shared__ int sums[1024];
  int t = threadIdx.x;
  int per = (N + 1023) / 1024;
  for (int pass = 0; pass < 2; ++pass) {
    const int* c = pass ? scnt : cnt;
    int* o = pass ? soffs : offs;
    int* u = pass ? scur : cur;
    int base = t * per;
    int s = 0;
    for (int i = 0; i < per; ++i) {
      int idx = base + i;
      if (idx < N) s += c[idx];
    }
    sums[t] = s;
    __syncthreads();
    for (int d = 1; d < 1024; d <<= 1) {
      int v = (t >= d) ? sums[t - d] : 0;
      __syncthreads();
      sums[t] += v;
      __syncthreads();
    }
    int run = (t == 0) ? 0 : sums[t - 1];
    for (int i = 0; i < per; ++i) {
      int idx = base + i;
      if (idx < N) {
        int cc = c[idx];
        o[idx] = run;
        u[idx] = run;
        run += cc;
      }
    }
    if (t == 1023) o[N] = sums[1023];
    __syncthreads();
  }
}

// fill both CSRs; sdpos links src-slot -> dst-slot so conv can write ye
// directly into the dst-CSR slot.
__global__ __launch_bounds__(256) void fill_kernel(
    const int* __restrict__ edges, int* __restrict__ cur, int* __restrict__ scur,
    const float* __restrict__ wxp_re, const float* __restrict__ wxp_im,
    const float* __restrict__ ln_re, const float* __restrict__ ln_im,
    int* __restrict__ src_l, float4* __restrict__ wln,
    int* __restrict__ selist, int* __restrict__ sdpos, int E) {
  int e = blockIdx.x * 256 + threadIdx.x;
  if (e >= E) return;
  int src = edges[2 * e];
  int dst = edges[2 * e + 1];
  int pos = atomicAdd(&cur[dst], 1);
  src_l[pos] = src;
  wln[pos] = make_float4(wxp_re[e], wxp_im[e], ln_re[e], ln_im[e]);
  int pos2 = atomicAdd(&scur[src], 1);
  selist[pos2] = e;
  sdpos[pos2] = pos;
}

// ---------------------------------------------------------------------------
// Edge conv in src-grouped order: wave per src node, g-row held in VGPRs,
// reused for all outgoing edges. Writes ye (8 complex) to dst-CSR slot.
// lane = es*8 + d.
// ---------------------------------------------------------------------------
__global__ __launch_bounds__(256, 4) void conv_src_kernel(
    const int* __restrict__ soffs, const int* __restrict__ selist,
    const int* __restrict__ sdpos,
    const float* __restrict__ sten_re, const float* __restrict__ sten_im,
    const float2* __restrict__ g2, float2* __restrict__ yebuf, int N) {
  int t = threadIdx.x;
  int m = blockIdx.x * 4 + (t >> 6);
  if (m >= N) return;
  int lane = t & 63;
  int es = lane >> 3;
  int d = lane & 7;
  float gr[18], gi[18];
  const float4* gq = (const float4*)(g2 + (size_t)m * 144 + d * 18);
#pragma unroll
  for (int p = 0; p < 9; ++p) {
    float4 v = gq[p];
    gr[2 * p] = v.x; gi[2 * p] = v.y;
    gr[2 * p + 1] = v.z; gi[2 * p + 1] = v.w;
  }
  int beg = soffs[m], end = soffs[m + 1];
  for (int i = beg + es; i < end; i += 8) {
    int e = selist[i];
    int ds = sdpos[i];
    const float2* pre = (const float2*)(sten_re + (size_t)e * 18);
    const float2* pim = (const float2*)(sten_im + (size_t)e * 18);
    float ar = 0.f, ai = 0.f;
#pragma unroll
    for (int p = 0; p < 9; ++p) {
      float2 a = pre[p];
      float2 b = pim[p];
      int rm = 2 * p;
      ar += a.x * gr[rm] - b.x * gi[rm];
      ai += a.x * gi[rm] + b.x * gr[rm];
      ar += a.y * gr[rm + 1] - b.y * gi[rm + 1];
      ai += a.y * gi[rm + 1] + b.y * gr[rm + 1];
    }
    yebuf[(size_t)ds * 8 + d] = make_float2(ar, ai);
  }
}

// ---------------------------------------------------------------------------
// Reduce ye over each node's contiguous dst-slot range + nonlinearity -> y
// ---------------------------------------------------------------------------
__global__ __launch_bounds__(256, 4) void ye_reduce_kernel(
    const int* __restrict__ offs, const float2* __restrict__ yebuf,
    const float* __restrict__ b_nl, float* __restrict__ y, int N) {
  int t = threadIdx.x;
  int n = blockIdx.x * 4 + (t >> 6);
  if (n >= N) return;
  int lane = t & 63;
  int es = lane >> 3;
  int d = lane & 7;
  int beg = offs[n], end = offs[n + 1];
  float ar = 0.f, ai = 0.f;
  for (int i = beg + es; i < end; i += 8) {
    float2 v = yebuf[(size_t)i * 8 + d];
    ar += v.x;
    ai += v.y;
  }
  ar += __shfl_xor(ar, 8);
  ai += __shfl_xor(ai, 8);
  ar += __shfl_xor(ar, 16);
  ai += __shfl_xor(ai, 16);
  ar += __shfl_xor(ar, 32);
  ai += __shfl_xor(ai, 32);
  if (lane < 8) {
    float mag = sqrtf(ar * ar + ai * ai);
    float s = fmaxf(mag + b_nl[d], 0.f) / (mag + EPSF);
    y[(size_t)n * 16 + 2 * d] = ar * s;
    y[(size_t)n * 16 + 2 * d + 1] = ai * s;
  }
}

// ---------------------------------------------------------------------------
// Histogram: 8 nodes/block, 32 lanes/node, d-major padded LDS layout.
// Writes desc[n][296] (disk-gathered, (d,k) order) to global.
// ---------------------------------------------------------------------------
__global__ __launch_bounds__(256, 4) void hist_kernel(
    const int* __restrict__ offs, const int* __restrict__ src_l,
    const float4* __restrict__ wln, const float* __restrict__ y,
    float* __restrict__ desc_g, int N) {
  __shared__ float hl[8 * 417];
  int t = threadIdx.x;
  int n0 = blockIdx.x * 8;
  for (int i = t; i < 8 * 417; i += 256) hl[i] = 0.f;
  __syncthreads();

  int v = t >> 5;
  int l = t & 31;
  int n = n0 + v;
  if (n < N) {
    int beg = offs[n], end = offs[n + 1];
    float* hv = hl + v * 417;
    for (int i = beg + l; i < end; i += 32) {
      int src = src_l[i];
      float4 w4 = wln[i];
      float wr = w4.x, wi = w4.y, lr = w4.z, li = w4.w;
      const float4* yp = (const float4*)(y + (size_t)src * 16);
#pragma unroll
      for (int p = 0; p < 4; ++p) {
        float4 yv = yp[p];
#pragma unroll
        for (int h = 0; h < 2; ++h) {
          int d = 2 * p + h;
          float yr = h ? yv.z : yv.x;
          float yi = h ? yv.w : yv.y;
          float fr = yr * wr - yi * wi;
          float fi = yr * wi + yi * wr;
          float fm = sqrtf(fr * fr + fi * fi);
          float inv = 1.f / (fm + EPSF);
          float cr = (lr * fr + li * fi) * inv;
          float ci = (li * fr - lr * fi) * inv;
          float gx = cr * 3.f + 3.f;
          float gy = ci * 3.f + 3.f;
          float x0f = floorf(gx), y0f = floorf(gy);
          float wx = gx - x0f, wy = gy - y0f;
          int x0i = min(max((int)x0f, 0), 6);
          int x1i = min(x0i + 1, 6);
          int y0i = min(max((int)y0f, 0), 6);
          int y1i = min(y0i + 1, 6);
          float* hd = hv + d * 52;
          atomicAdd(hd + x0i * 7 + y0i, fm * (1.f - wx) * (1.f - wy));
          atomicAdd(hd + x1i * 7 + y0i, fm * wx * (1.f - wy));
          atomicAdd(hd + x0i * 7 + y1i, fm * (1.f - wx) * wy);
          atomicAdd(hd + x1i * 7 + y1i, fm * wx * wy);
        }
      }
    }
  }
  __syncthreads();

  for (int i = t; i < 8 * 296; i += 256) {
    int vv = i / 296;
    int q = i - vv * 296;
    int d = q / 37;
    int k = q - d * 37;
    int nn = n0 + vv;
    if (nn < N) desc_g[(size_t)nn * 296 + q] = hl[vv * 417 + d * 52 + DISK[k]];
  }
}

// ---------------------------------------------------------------------------
// mlp1: h1 = relu(desc @ W1^T + b1).  64 nodes/block, 256 threads.
// Thread tile: 8 nodes x 4 j (j = jt + 32*jj). K chunks of 40.
// bufA [64][40] node-major; bufB k-major stride 133 (odd -> <=2-way, free).
// LDS = 31.5 KB -> 5 blocks/CU.
// ---------------------------------------------------------------------------
__global__ __launch_bounds__(256, 4) void mlp1_kernel(
    const float* __restrict__ desc_g, const float* __restrict__ W1,
    const float* __restrict__ b1, float* __restrict__ h1_g, int N) {
  __shared__ float bufA[64 * 40];
  __shared__ float bufB[40 * 133];
  int t = threadIdx.x;
  int n0 = blockIdx.x * 64;
  int jt = t & 31;
  int nb = (t >> 5) * 8;

  float acc[8][4];
#pragma unroll
  for (int jj = 0; jj < 4; ++jj) {
    float bb = b1[jt + 32 * jj];
#pragma unroll
    for (int i = 0; i < 8; ++i) acc[i][jj] = bb;
  }

  for (int k0 = 0; k0 < 296; k0 += 40) {
    int kc = min(40, 296 - k0);
    int kc4 = kc >> 2;
    // stage A: [64][kc]
    for (int i = t; i < 64 * kc4; i += 256) {
      int r = i / kc4, c4 = (i - r * kc4) * 4;
      int n = n0 + r;
      float4 v = (n < N) ? *(const float4*)&desc_g[(size_t)n * 296 + k0 + c4]
                         : make_float4(0.f, 0.f, 0.f, 0.f);
      *(float4*)&bufA[r * 40 + c4] = v;
    }
    // stage B k-major: bufB[kk*133 + j]
    for (int i = t; i < 128 * kc4; i += 256) {
      int r = i / kc4, c4 = (i - r * kc4) * 4;
      float4 w = *(const float4*)&W1[(size_t)r * 296 + k0 + c4];
      bufB[(c4 + 0) * 133 + r] = w.x;
      bufB[(c4 + 1) * 133 + r] = w.y;
      bufB[(c4 + 2) * 133 + r] = w.z;
      bufB[(c4 + 3) * 133 + r] = w.w;
    }
    __syncthreads();
    for (int kk = 0; kk < kc; kk += 4) {
      float4 a[8];
#pragma unroll
      for (int i = 0; i < 8; ++i) a[i] = *(const float4*)&bufA[(nb + i) * 40 + kk];
#pragma unroll
      for (int q = 0; q < 4; ++q) {
        float bv[4];
#pragma unroll
        for (int jj = 0; jj < 4; ++jj) bv[jj] = bufB[(kk + q) * 133 + jt + 32 * jj];
#pragma unroll
        for (int i = 0; i < 8; ++i) {
          float av = (q == 0) ? a[i].x : (q == 1) ? a[i].y : (q == 2) ? a[i].z : a[i].w;
#pragma unroll
          for (int jj = 0; jj < 4; ++jj) acc[i][jj] += av * bv[jj];
        }
      }
    }
    __syncthreads();
  }
#pragma unroll
  for (int i = 0; i < 8; ++i) {
    int n = n0 + nb + i;
    if (n < N) {
#pragma unroll
      for (int jj = 0; jj < 4; ++jj)
        h1_g[(size_t)n * 128 + jt + 32 * jj] = fmaxf(acc[i][jj], 0.f);
    }
  }
}

// ---------------------------------------------------------------------------
// mlp23: h2 = relu(h1 @ W2^T + b2); out = h2 @ W3^T + b3 + bres + rmag @ Wres^T
// 64 nodes/block, 256 threads; thread tile 8 nodes x 2 j.
// ---------------------------------------------------------------------------
__global__ __launch_bounds__(256, 4) void mlp23_kernel(
    const float* __restrict__ h1_g,
    const float* __restrict__ x_re, const float* __restrict__ x_im,
    const float* __restrict__ W2, const float* __restrict__ b2,
    const float* __restrict__ W3, const float* __restrict__ b3,
    const float* __restrict__ Wres, const float* __restrict__ bres,
    float* __restrict__ out, int N) {
  __shared__ float bufA[64 * 68];
  __shared__ float bufB[64 * 67];
  __shared__ float h2s[64 * 68];
  __shared__ float rmag[64][8];
  int t = threadIdx.x;
  int n0 = blockIdx.x * 64;
  int jt = t & 31;
  int nb = (t >> 5) * 8;

  // rmag: 64 nodes x 8 ch staged by 256 threads (2 each)
  for (int i = t; i < 512; i += 256) {
    int v = i >> 3, c = i & 7;
    int n = n0 + v;
    if (n < N) {
      float xr = x_re[n * 8 + c], xi = x_im[n * 8 + c];
      rmag[v][c] = sqrtf(xr * xr + xi * xi + EPSF);
    } else {
      rmag[v][c] = 0.f;
    }
  }

  // ---------------- Layer 2 ----------------
  float acc2[8][2];
#pragma unroll
  for (int jj = 0; jj < 2; ++jj) {
    float bb = b2[jt + 32 * jj];
#pragma unroll
    for (int i = 0; i < 8; ++i) acc2[i][jj] = bb;
  }
  for (int k0 = 0; k0 < 128; k0 += 64) {
    // stage A chunk [64][64] from h1_g
    for (int i = t; i < 64 * 16; i += 256) {
      int r = i >> 4, c4 = (i & 15) * 4;
      int n = n0 + r;
      float4 v = (n < N) ? *(const float4*)&h1_g[(size_t)n * 128 + k0 + c4]
                         : make_float4(0.f, 0.f, 0.f, 0.f);
      *(float4*)&bufA[r * 68 + c4] = v;
    }
    // stage W2 chunk k-major
    for (int i = t; i < 64 * 16; i += 256) {
      int r = i >> 4, c4 = (i & 15) * 4;
      float4 w = *(const float4*)&W2[(size_t)r * 128 + k0 + c4];
      bufB[(c4 + 0) * 67 + r] = w.x;
      bufB[(c4 + 1) * 67 + r] = w.y;
      bufB[(c4 + 2) * 67 + r] = w.z;
      bufB[(c4 + 3) * 67 + r] = w.w;
    }
    __syncthreads();
    for (int kk = 0; kk < 64; kk += 4) {
      float4 a[8];
#pragma unroll
      for (int i = 0; i < 8; ++i) a[i] = *(const float4*)&bufA[(nb + i) * 68 + kk];
#pragma unroll
      for (int q = 0; q < 4; ++q) {
        float bv[2];
#pragma unroll
        for (int jj = 0; jj < 2; ++jj) bv[jj] = bufB[(kk + q) * 67 + jt + 32 * jj];
#pragma unroll
        for (int i = 0; i < 8; ++i) {
          float av = (q == 0) ? a[i].x : (q == 1) ? a[i].y : (q == 2) ? a[i].z : a[i].w;
#pragma unroll
          for (int jj = 0; jj < 2; ++jj) acc2[i][jj] += av * bv[jj];
        }
      }
    }
    __syncthreads();
  }
#pragma unroll
  for (int i = 0; i < 8; ++i)
#pragma unroll
    for (int jj = 0; jj < 2; ++jj)
      h2s[(nb + i) * 68 + jt + 32 * jj] = fmaxf(acc2[i][jj], 0.f);

  // stage W3 k-major (reuse bufB)
  __syncthreads();
  for (int i = t; i < 64 * 16; i += 256) {
    int r = i >> 4, c4 = (i & 15) * 4;
    float4 w = *(const float4*)&W3[(size_t)r * 64 + c4];
    bufB[(c4 + 0) * 67 + r] = w.x;
    bufB[(c4 + 1) * 67 + r] = w.y;
    bufB[(c4 + 2) * 67 + r] = w.z;
    bufB[(c4 + 3) * 67 + r] = w.w;
  }
  __syncthreads();

  // ---------------- Layer 3 + residual ----------------
  float acc3[8][2];
#pragma unroll
  for (int jj = 0; jj < 2; ++jj) {
    float bb = b3[jt + 32 * jj] + bres[jt + 32 * jj];
#pragma unroll
    for (int i = 0; i < 8; ++i) acc3[i][jj] = bb;
  }
  for (int kk = 0; kk < 64; kk += 4) {
    float4 a[8];
#pragma unroll
    for (int i = 0; i < 8; ++i) a[i] = *(const float4*)&h2s[(nb + i) * 68 + kk];
#pragma unroll
    for (int q = 0; q < 4; ++q) {
      float bv[2];
#pragma unroll
      for (int jj = 0; jj < 2; ++jj) bv[jj] = bufB[(kk + q) * 67 + jt + 32 * jj];
#pragma unroll
      for (int i = 0; i < 8; ++i) {
        float av = (q == 0) ? a[i].x : (q == 1) ? a[i].y : (q == 2) ? a[i].z : a[i].w;
#pragma unroll
        for (int jj = 0; jj < 2; ++jj) acc3[i][jj] += av * bv[jj];
      }
    }
  }
#pragma unroll
  for (int jj = 0; jj < 2; ++jj) {
    int j = jt + 32 * jj;
    float wrr[8];
    const float* wp = Wres + (size_t)j * 8;
#pragma unroll
    for (int c = 0; c < 8; ++c) wrr[c] = wp[c];
#pragma unroll
    for (int i = 0; i < 8; ++i) {
      float s = acc3[i][jj];
#pragma unroll
      for (int c = 0; c < 8; ++c) s += wrr[c] * rmag[nb + i][c];
      int n = n0 + nb + i;
      if (n < N) out[(size_t)n * 64 + j] = s;
    }
  }
}

extern "C" void kernel_launch(void* const* d_in, const int* in_sizes, int n_in,
                              void* d_out, int out_size, void* d_ws, size_t ws_size,
                              hipStream_t stream) {
  (void)n_in; (void)out_size; (void)ws_size;
  const float* x_re = (const float*)d_in[0];
  const float* x_im = (const float*)d_in[1];
  const int* edges = (const int*)d_in[2];
  const float* sten_re = (const float*)d_in[3];
  const float* sten_im = (const float*)d_in[4];
  const float* ln_re = (const float*)d_in[5];
  const float* ln_im = (const float*)d_in[6];
  const float* wxp_re = (const float*)d_in[7];
  const float* wxp_im = (const float*)d_in[8];
  const float* W_conv = (const float*)d_in[9];
  const float* phase = (const float*)d_in[10];
  const float* b_nl = (const float*)d_in[11];
  const float* W1 = (const float*)d_in[12];
  const float* b1 = (const float*)d_in[13];
  const float* W2 = (const float*)d_in[14];
  const float* b2 = (const float*)d_in[15];
  const float* W3 = (const float*)d_in[16];
  const float* b3 = (const float*)d_in[17];
  const float* Wres = (const float*)d_in[18];
  const float* bres = (const float*)d_in[19];
  float* out = (float*)d_out;

  int N = in_sizes[0] / 8;
  int E = in_sizes[2] / 2;

  // workspace layout (16B-aligned blocks first)
  float* ws = (float*)d_ws;
  float4* wln = (float4*)ws;                          // E float4
  float* g2f = ws + (size_t)E * 4;                    // N*288 floats
  float2* g2 = (float2*)g2f;
  float* h1_g = g2f;                                  // N*128 <= N*288; g dead by mlp1
  float* y = g2f + (size_t)N * 288;                   // N*16
  float* yebuf_f = y + (size_t)N * 16;                // E*16 floats; desc_g aliases
  float2* yebuf = (float2*)yebuf_f;
  float* desc_g = yebuf_f;                            // N*296 <= E*16; ye dead by then
  int* cnt = (int*)(yebuf_f + (size_t)E * 16);        // N
  int* offs = cnt + N;                                // N+1
  int* cur = offs + N + 1;                            // N
  int* scnt = cur + N;                                // N
  int* soffs = scnt + N;                              // N+1
  int* scur = soffs + N + 1;                          // N
  int* selist = scur + N;                             // E
  int* sdpos = selist + E;                            // E
  int* src_l = sdpos + E;                             // E

  hipMemsetAsync(cnt, 0, (size_t)N * sizeof(int), stream);
  hipMemsetAsync(scnt, 0, (size_t)N * sizeof(int), stream);

  g_kernel<<<(N * 144 + 255) / 256, 256, 0, stream>>>(x_re, x_im, W_conv, phase, g2, N);
  count_kernel<<<(E + 255) / 256, 256, 0, stream>>>(edges, cnt, scnt, E);
  scan_dual_kernel<<<1, 1024, 0, stream>>>(cnt, offs, cur, scnt, soffs, scur, N);
  fill_kernel<<<(E + 255) / 256, 256, 0, stream>>>(edges, cur, scur, wxp_re, wxp_im,
                                                   ln_re, ln_im, src_l, wln,
                                                   selist, sdpos, E);
  conv_src_kernel<<<(N + 3) / 4, 256, 0, stream>>>(soffs, selist, sdpos, sten_re,
                                                   sten_im, g2, yebuf, N);
  ye_reduce_kernel<<<(N + 3) / 4, 256, 0, stream>>>(offs, yebuf, b_nl, y, N);
  hist_kernel<<<(N + 7) / 8, 256, 0, stream>>>(offs, src_l, wln, y, desc_g, N);
  mlp1_kernel<<<(N + 63) / 64, 256, 0, stream>>>(desc_g, W1, b1, h1_g, N);
  mlp23_kernel<<<(N + 63) / 64, 256, 0, stream>>>(h1_g, x_re, x_im, W2, b2,
                                                  W3, b3, Wres, bres, out, N);
}

// Round 7
// 613.250 us; speedup vs baseline: 1.1595x; 1.0106x over previous
//
#include <hip/hip_runtime.h>
#include <math.h>

#define EPSF 1e-6f

__device__ __constant__ int DISK[37] = {
    2, 3, 4,
    8, 9, 10, 11, 12,
    14, 15, 16, 17, 18, 19, 20,
    21, 22, 23, 24, 25, 26, 27,
    28, 29, 30, 31, 32, 33, 34,
    36, 37, 38, 39, 40,
    44, 45, 46};

// ---------------------------------------------------------------------------
// g[n, d, rm] = sum_c Wc[d, c, rm] * x[n, c];  Wc = W_conv * exp(i*phase)
// g stored interleaved float2, layout [n][d*18+rm]
// ---------------------------------------------------------------------------
__global__ __launch_bounds__(256) void g_kernel(
    const float* __restrict__ x_re, const float* __restrict__ x_im,
    const float* __restrict__ W_conv, const float* __restrict__ phase,
    float2* __restrict__ g2, int N) {
  __shared__ float wc_re[1152];
  __shared__ float wc_im[1152];
  int t = threadIdx.x;
  for (int i = t; i < 1152; i += 256) {
    int dc = i / 18;
    float w = W_conv[i];
    float ph = phase[dc];
    wc_re[i] = w * cosf(ph);
    wc_im[i] = w * sinf(ph);
  }
  __syncthreads();
  int gid = blockIdx.x * 256 + t;
  int total = N * 144;
  if (gid >= total) return;
  int n = gid / 144;
  int q = gid - n * 144;  // d*18 + rm
  int d = q / 18;
  int rm = q - d * 18;
  const float* xr = x_re + n * 8;
  const float* xi = x_im + n * 8;
  float ar = 0.f, ai = 0.f;
#pragma unroll
  for (int c = 0; c < 8; ++c) {
    float wr = wc_re[(d * 8 + c) * 18 + rm];
    float wi = wc_im[(d * 8 + c) * 18 + rm];
    float vr = xr[c], vi = xi[c];
    ar += wr * vr - wi * vi;
    ai += wr * vi + wi * vr;
  }
  g2[gid] = make_float2(ar, ai);
}

// ---------------------------------------------------------------------------
// CSR build: count both dst (cnt) and src (scnt) degrees in one pass
// ---------------------------------------------------------------------------
__global__ __launch_bounds__(256) void count_kernel(const int* __restrict__ edges,
                                                    int* __restrict__ cnt,
                                                    int* __restrict__ scnt, int E) {
  int e = blockIdx.x * 256 + threadIdx.x;
  if (e >= E) return;
  atomicAdd(&cnt[edges[2 * e + 1]], 1);
  atomicAdd(&scnt[edges[2 * e]], 1);
}

// Single-block dual exclusive scan: cnt->offs,cur and scnt->soffs,scur
__global__ __launch_bounds__(1024) void scan_dual_kernel(
    const int* __restrict__ cnt, int* __restrict__ offs, int* __restrict__ cur,
    const int* __restrict__ scnt, int* __restrict__ soffs, int* __restrict__ scur,
    int N) {
  __shared__ int sums[1024];
  int t = threadIdx.x;
  int per = (N + 1023) / 1024;
  for (int pass = 0; pass < 2; ++pass) {
    const int* c = pass ? scnt : cnt;
    int* o = pass ? soffs : offs;
    int* u = pass ? scur : cur;
    int base = t * per;
    int s = 0;
    for (int i = 0; i < per; ++i) {
      int idx = base + i;
      if (idx < N) s += c[idx];
    }
    sums[t] = s;
    __syncthreads();
    for (int d = 1; d < 1024; d <<= 1) {
      int v = (t >= d) ? sums[t - d] : 0;
      __syncthreads();
      sums[t] += v;
      __syncthreads();
    }
    int run = (t == 0) ? 0 : sums[t - 1];
    for (int i = 0; i < per; ++i) {
      int idx = base + i;
      if (idx < N) {
        int cc = c[idx];
        o[idx] = run;
        u[idx] = run;
        run += cc;
      }
    }
    if (t == 1023) o[N] = sums[1023];
    __syncthreads();
  }
}

// fill both CSRs; sdpos links src-slot -> dst-slot so conv can write ye
// directly into the dst-CSR slot.
__global__ __launch_bounds__(256) void fill_kernel(
    const int* __restrict__ edges, int* __restrict__ cur, int* __restrict__ scur,
    const float* __restrict__ wxp_re, const float* __restrict__ wxp_im,
    const float* __restrict__ ln_re, const float* __restrict__ ln_im,
    int* __restrict__ src_l, float4* __restrict__ wln,
    int* __restrict__ selist, int* __restrict__ sdpos, int E) {
  int e = blockIdx.x * 256 + threadIdx.x;
  if (e >= E) return;
  int src = edges[2 * e];
  int dst = edges[2 * e + 1];
  int pos = atomicAdd(&cur[dst], 1);
  src_l[pos] = src;
  wln[pos] = make_float4(wxp_re[e], wxp_im[e], ln_re[e], ln_im[e]);
  int pos2 = atomicAdd(&scur[src], 1);
  selist[pos2] = e;
  sdpos[pos2] = pos;
}

// ---------------------------------------------------------------------------
// Edge conv in src-grouped order: wave per src node, g-row held in VGPRs,
// reused for all outgoing edges. Writes ye (8 complex) to dst-CSR slot.
// lane = es*8 + d.
// ---------------------------------------------------------------------------
__global__ __launch_bounds__(256, 4) void conv_src_kernel(
    const int* __restrict__ soffs, const int* __restrict__ selist,
    const int* __restrict__ sdpos,
    const float* __restrict__ sten_re, const float* __restrict__ sten_im,
    const float2* __restrict__ g2, float2* __restrict__ yebuf, int N) {
  int t = threadIdx.x;
  int m = blockIdx.x * 4 + (t >> 6);
  if (m >= N) return;
  int lane = t & 63;
  int es = lane >> 3;
  int d = lane & 7;
  float gr[18], gi[18];
  const float4* gq = (const float4*)(g2 + (size_t)m * 144 + d * 18);
#pragma unroll
  for (int p = 0; p < 9; ++p) {
    float4 v = gq[p];
    gr[2 * p] = v.x; gi[2 * p] = v.y;
    gr[2 * p + 1] = v.z; gi[2 * p + 1] = v.w;
  }
  int beg = soffs[m], end = soffs[m + 1];
  for (int i = beg + es; i < end; i += 8) {
    int e = selist[i];
    int ds = sdpos[i];
    const float2* pre = (const float2*)(sten_re + (size_t)e * 18);
    const float2* pim = (const float2*)(sten_im + (size_t)e * 18);
    float ar = 0.f, ai = 0.f;
#pragma unroll
    for (int p = 0; p < 9; ++p) {
      float2 a = pre[p];
      float2 b = pim[p];
      int rm = 2 * p;
      ar += a.x * gr[rm] - b.x * gi[rm];
      ai += a.x * gi[rm] + b.x * gr[rm];
      ar += a.y * gr[rm + 1] - b.y * gi[rm + 1];
      ai += a.y * gi[rm + 1] + b.y * gr[rm + 1];
    }
    yebuf[(size_t)ds * 8 + d] = make_float2(ar, ai);
  }
}

// ---------------------------------------------------------------------------
// Reduce ye over each node's contiguous dst-slot range + nonlinearity -> y
// ---------------------------------------------------------------------------
__global__ __launch_bounds__(256, 4) void ye_reduce_kernel(
    const int* __restrict__ offs, const float2* __restrict__ yebuf,
    const float* __restrict__ b_nl, float* __restrict__ y, int N) {
  int t = threadIdx.x;
  int n = blockIdx.x * 4 + (t >> 6);
  if (n >= N) return;
  int lane = t & 63;
  int es = lane >> 3;
  int d = lane & 7;
  int beg = offs[n], end = offs[n + 1];
  float ar = 0.f, ai = 0.f;
  for (int i = beg + es; i < end; i += 8) {
    float2 v = yebuf[(size_t)i * 8 + d];
    ar += v.x;
    ai += v.y;
  }
  ar += __shfl_xor(ar, 8);
  ai += __shfl_xor(ai, 8);
  ar += __shfl_xor(ar, 16);
  ai += __shfl_xor(ai, 16);
  ar += __shfl_xor(ar, 32);
  ai += __shfl_xor(ai, 32);
  if (lane < 8) {
    float mag = sqrtf(ar * ar + ai * ai);
    float s = fmaxf(mag + b_nl[d], 0.f) / (mag + EPSF);
    y[(size_t)n * 16 + 2 * d] = ar * s;
    y[(size_t)n * 16 + 2 * d + 1] = ai * s;
  }
}

// ---------------------------------------------------------------------------
// Histogram: 8 nodes/block, 32 lanes/node, lane = es*8 + d (es: edge slot,
// d: channel). Concurrent atomics now span 8 distinct d per node -> same-
// address LDS-atomic serialization bounded by 4 (was 32). y[src] read is one
// coalesced 64B line across the 8 d-lanes.
// hl layout [v*417 + d*52 + bin]; d*52 mod 32 hits 8 distinct banks.
// ---------------------------------------------------------------------------
__global__ __launch_bounds__(256, 4) void hist_kernel(
    const int* __restrict__ offs, const int* __restrict__ src_l,
    const float4* __restrict__ wln, const float* __restrict__ y,
    float* __restrict__ desc_g, int N) {
  __shared__ float hl[8 * 417];
  int t = threadIdx.x;
  int n0 = blockIdx.x * 8;
  for (int i = t; i < 8 * 417; i += 256) hl[i] = 0.f;
  __syncthreads();

  int v = t >> 5;
  int es = (t >> 3) & 3;
  int d = t & 7;
  int n = n0 + v;
  if (n < N) {
    int beg = offs[n], end = offs[n + 1];
    float* hd = hl + v * 417 + d * 52;
    for (int i = beg + es; i < end; i += 4) {
      int src = src_l[i];
      float4 w4 = wln[i];
      float wr = w4.x, wi = w4.y, lr = w4.z, li = w4.w;
      float2 yv = *(const float2*)(y + (size_t)src * 16 + 2 * d);
      float yr = yv.x, yi = yv.y;
      float fr = yr * wr - yi * wi;
      float fi = yr * wi + yi * wr;
      float fm = sqrtf(fr * fr + fi * fi);
      float inv = 1.f / (fm + EPSF);
      float cr = (lr * fr + li * fi) * inv;
      float ci = (li * fr - lr * fi) * inv;
      float gx = cr * 3.f + 3.f;
      float gy = ci * 3.f + 3.f;
      float x0f = floorf(gx), y0f = floorf(gy);
      float wx = gx - x0f, wy = gy - y0f;
      int x0i = min(max((int)x0f, 0), 6);
      int x1i = min(x0i + 1, 6);
      int y0i = min(max((int)y0f, 0), 6);
      int y1i = min(y0i + 1, 6);
      atomicAdd(hd + x0i * 7 + y0i, fm * (1.f - wx) * (1.f - wy));
      atomicAdd(hd + x1i * 7 + y0i, fm * wx * (1.f - wy));
      atomicAdd(hd + x0i * 7 + y1i, fm * (1.f - wx) * wy);
      atomicAdd(hd + x1i * 7 + y1i, fm * wx * wy);
    }
  }
  __syncthreads();

  for (int i = t; i < 8 * 296; i += 256) {
    int vv = i / 296;
    int q = i - vv * 296;
    int dd = q / 37;
    int k = q - dd * 37;
    int nn = n0 + vv;
    if (nn < N) desc_g[(size_t)nn * 296 + q] = hl[vv * 417 + dd * 52 + DISK[k]];
  }
}

// ---------------------------------------------------------------------------
// mlp1: h1 = relu(desc @ W1^T + b1).  64 nodes/block, 256 threads.
// Thread tile: 8 nodes x 4 j (j = jt + 32*jj). K chunks of 40.
// bufA [64][40] node-major; bufB k-major stride 133 (odd -> <=2-way, free).
// ---------------------------------------------------------------------------
__global__ __launch_bounds__(256, 4) void mlp1_kernel(
    const float* __restrict__ desc_g, const float* __restrict__ W1,
    const float* __restrict__ b1, float* __restrict__ h1_g, int N) {
  __shared__ float bufA[64 * 40];
  __shared__ float bufB[40 * 133];
  int t = threadIdx.x;
  int n0 = blockIdx.x * 64;
  int jt = t & 31;
  int nb = (t >> 5) * 8;

  float acc[8][4];
#pragma unroll
  for (int jj = 0; jj < 4; ++jj) {
    float bb = b1[jt + 32 * jj];
#pragma unroll
    for (int i = 0; i < 8; ++i) acc[i][jj] = bb;
  }

  for (int k0 = 0; k0 < 296; k0 += 40) {
    int kc = min(40, 296 - k0);
    int kc4 = kc >> 2;
    // stage A: [64][kc]
    for (int i = t; i < 64 * kc4; i += 256) {
      int r = i / kc4, c4 = (i - r * kc4) * 4;
      int n = n0 + r;
      float4 v = (n < N) ? *(const float4*)&desc_g[(size_t)n * 296 + k0 + c4]
                         : make_float4(0.f, 0.f, 0.f, 0.f);
      *(float4*)&bufA[r * 40 + c4] = v;
    }
    // stage B k-major: bufB[kk*133 + j]
    for (int i = t; i < 128 * kc4; i += 256) {
      int r = i / kc4, c4 = (i - r * kc4) * 4;
      float4 w = *(const float4*)&W1[(size_t)r * 296 + k0 + c4];
      bufB[(c4 + 0) * 133 + r] = w.x;
      bufB[(c4 + 1) * 133 + r] = w.y;
      bufB[(c4 + 2) * 133 + r] = w.z;
      bufB[(c4 + 3) * 133 + r] = w.w;
    }
    __syncthreads();
    for (int kk = 0; kk < kc; kk += 4) {
      float4 a[8];
#pragma unroll
      for (int i = 0; i < 8; ++i) a[i] = *(const float4*)&bufA[(nb + i) * 40 + kk];
#pragma unroll
      for (int q = 0; q < 4; ++q) {
        float bv[4];
#pragma unroll
        for (int jj = 0; jj < 4; ++jj) bv[jj] = bufB[(kk + q) * 133 + jt + 32 * jj];
#pragma unroll
        for (int i = 0; i < 8; ++i) {
          float av = (q == 0) ? a[i].x : (q == 1) ? a[i].y : (q == 2) ? a[i].z : a[i].w;
#pragma unroll
          for (int jj = 0; jj < 4; ++jj) acc[i][jj] += av * bv[jj];
        }
      }
    }
    __syncthreads();
  }
#pragma unroll
  for (int i = 0; i < 8; ++i) {
    int n = n0 + nb + i;
    if (n < N) {
#pragma unroll
      for (int jj = 0; jj < 4; ++jj)
        h1_g[(size_t)n * 128 + jt + 32 * jj] = fmaxf(acc[i][jj], 0.f);
    }
  }
}

// ---------------------------------------------------------------------------
// mlp23: h2 = relu(h1 @ W2^T + b2); out = h2 @ W3^T + b3 + bres + rmag @ Wres^T
// 64 nodes/block, 256 threads; thread tile 8 nodes x 2 j.
// ---------------------------------------------------------------------------
__global__ __launch_bounds__(256, 4) void mlp23_kernel(
    const float* __restrict__ h1_g,
    const float* __restrict__ x_re, const float* __restrict__ x_im,
    const float* __restrict__ W2, const float* __restrict__ b2,
    const float* __restrict__ W3, const float* __restrict__ b3,
    const float* __restrict__ Wres, const float* __restrict__ bres,
    float* __restrict__ out, int N) {
  __shared__ float bufA[64 * 68];
  __shared__ float bufB[64 * 67];
  __shared__ float h2s[64 * 68];
  __shared__ float rmag[64][8];
  int t = threadIdx.x;
  int n0 = blockIdx.x * 64;
  int jt = t & 31;
  int nb = (t >> 5) * 8;

  // rmag: 64 nodes x 8 ch staged by 256 threads (2 each)
  for (int i = t; i < 512; i += 256) {
    int v = i >> 3, c = i & 7;
    int n = n0 + v;
    if (n < N) {
      float xr = x_re[n * 8 + c], xi = x_im[n * 8 + c];
      rmag[v][c] = sqrtf(xr * xr + xi * xi + EPSF);
    } else {
      rmag[v][c] = 0.f;
    }
  }

  // ---------------- Layer 2 ----------------
  float acc2[8][2];
#pragma unroll
  for (int jj = 0; jj < 2; ++jj) {
    float bb = b2[jt + 32 * jj];
#pragma unroll
    for (int i = 0; i < 8; ++i) acc2[i][jj] = bb;
  }
  for (int k0 = 0; k0 < 128; k0 += 64) {
    // stage A chunk [64][64] from h1_g
    for (int i = t; i < 64 * 16; i += 256) {
      int r = i >> 4, c4 = (i & 15) * 4;
      int n = n0 + r;
      float4 v = (n < N) ? *(const float4*)&h1_g[(size_t)n * 128 + k0 + c4]
                         : make_float4(0.f, 0.f, 0.f, 0.f);
      *(float4*)&bufA[r * 68 + c4] = v;
    }
    // stage W2 chunk k-major
    for (int i = t; i < 64 * 16; i += 256) {
      int r = i >> 4, c4 = (i & 15) * 4;
      float4 w = *(const float4*)&W2[(size_t)r * 128 + k0 + c4];
      bufB[(c4 + 0) * 67 + r] = w.x;
      bufB[(c4 + 1) * 67 + r] = w.y;
      bufB[(c4 + 2) * 67 + r] = w.z;
      bufB[(c4 + 3) * 67 + r] = w.w;
    }
    __syncthreads();
    for (int kk = 0; kk < 64; kk += 4) {
      float4 a[8];
#pragma unroll
      for (int i = 0; i < 8; ++i) a[i] = *(const float4*)&bufA[(nb + i) * 68 + kk];
#pragma unroll
      for (int q = 0; q < 4; ++q) {
        float bv[2];
#pragma unroll
        for (int jj = 0; jj < 2; ++jj) bv[jj] = bufB[(kk + q) * 67 + jt + 32 * jj];
#pragma unroll
        for (int i = 0; i < 8; ++i) {
          float av = (q == 0) ? a[i].x : (q == 1) ? a[i].y : (q == 2) ? a[i].z : a[i].w;
#pragma unroll
          for (int jj = 0; jj < 2; ++jj) acc2[i][jj] += av * bv[jj];
        }
      }
    }
    __syncthreads();
  }
#pragma unroll
  for (int i = 0; i < 8; ++i)
#pragma unroll
    for (int jj = 0; jj < 2; ++jj)
      h2s[(nb + i) * 68 + jt + 32 * jj] = fmaxf(acc2[i][jj], 0.f);

  // stage W3 k-major (reuse bufB)
  __syncthreads();
  for (int i = t; i < 64 * 16; i += 256) {
    int r = i >> 4, c4 = (i & 15) * 4;
    float4 w = *(const float4*)&W3[(size_t)r * 64 + c4];
    bufB[(c4 + 0) * 67 + r] = w.x;
    bufB[(c4 + 1) * 67 + r] = w.y;
    bufB[(c4 + 2) * 67 + r] = w.z;
    bufB[(c4 + 3) * 67 + r] = w.w;
  }
  __syncthreads();

  // ---------------- Layer 3 + residual ----------------
  float acc3[8][2];
#pragma unroll
  for (int jj = 0; jj < 2; ++jj) {
    float bb = b3[jt + 32 * jj] + bres[jt + 32 * jj];
#pragma unroll
    for (int i = 0; i < 8; ++i) acc3[i][jj] = bb;
  }
  for (int kk = 0; kk < 64; kk += 4) {
    float4 a[8];
#pragma unroll
    for (int i = 0; i < 8; ++i) a[i] = *(const float4*)&h2s[(nb + i) * 68 + kk];
#pragma unroll
    for (int q = 0; q < 4; ++q) {
      float bv[2];
#pragma unroll
      for (int jj = 0; jj < 2; ++jj) bv[jj] = bufB[(kk + q) * 67 + jt + 32 * jj];
#pragma unroll
      for (int i = 0; i < 8; ++i) {
        float av = (q == 0) ? a[i].x : (q == 1) ? a[i].y : (q == 2) ? a[i].z : a[i].w;
#pragma unroll
        for (int jj = 0; jj < 2; ++jj) acc3[i][jj] += av * bv[jj];
      }
    }
  }
#pragma unroll
  for (int jj = 0; jj < 2; ++jj) {
    int j = jt + 32 * jj;
    float wrr[8];
    const float* wp = Wres + (size_t)j * 8;
#pragma unroll
    for (int c = 0; c < 8; ++c) wrr[c] = wp[c];
#pragma unroll
    for (int i = 0; i < 8; ++i) {
      float s = acc3[i][jj];
#pragma unroll
      for (int c = 0; c < 8; ++c) s += wrr[c] * rmag[nb + i][c];
      int n = n0 + nb + i;
      if (n < N) out[(size_t)n * 64 + j] = s;
    }
  }
}

extern "C" void kernel_launch(void* const* d_in, const int* in_sizes, int n_in,
                              void* d_out, int out_size, void* d_ws, size_t ws_size,
                              hipStream_t stream) {
  (void)n_in; (void)out_size; (void)ws_size;
  const float* x_re = (const float*)d_in[0];
  const float* x_im = (const float*)d_in[1];
  const int* edges = (const int*)d_in[2];
  const float* sten_re = (const float*)d_in[3];
  const float* sten_im = (const float*)d_in[4];
  const float* ln_re = (const float*)d_in[5];
  const float* ln_im = (const float*)d_in[6];
  const float* wxp_re = (const float*)d_in[7];
  const float* wxp_im = (const float*)d_in[8];
  const float* W_conv = (const float*)d_in[9];
  const float* phase = (const float*)d_in[10];
  const float* b_nl = (const float*)d_in[11];
  const float* W1 = (const float*)d_in[12];
  const float* b1 = (const float*)d_in[13];
  const float* W2 = (const float*)d_in[14];
  const float* b2 = (const float*)d_in[15];
  const float* W3 = (const float*)d_in[16];
  const float* b3 = (const float*)d_in[17];
  const float* Wres = (const float*)d_in[18];
  const float* bres = (const float*)d_in[19];
  float* out = (float*)d_out;

  int N = in_sizes[0] / 8;
  int E = in_sizes[2] / 2;

  // workspace layout (16B-aligned blocks first)
  float* ws = (float*)d_ws;
  float4* wln = (float4*)ws;                          // E float4
  float* g2f = ws + (size_t)E * 4;                    // N*288 floats
  float2* g2 = (float2*)g2f;
  float* h1_g = g2f;                                  // N*128 <= N*288; g dead by mlp1
  float* y = g2f + (size_t)N * 288;                   // N*16
  float* yebuf_f = y + (size_t)N * 16;                // E*16 floats; desc_g aliases
  float2* yebuf = (float2*)yebuf_f;
  float* desc_g = yebuf_f;                            // N*296 <= E*16; ye dead by then
  int* cnt = (int*)(yebuf_f + (size_t)E * 16);        // N
  int* offs = cnt + N;                                // N+1
  int* cur = offs + N + 1;                            // N
  int* scnt = cur + N;                                // N
  int* soffs = scnt + N;                              // N+1
  int* scur = soffs + N + 1;                          // N
  int* selist = scur + N;                             // E
  int* sdpos = selist + E;                            // E
  int* src_l = sdpos + E;                             // E

  hipMemsetAsync(cnt, 0, (size_t)N * sizeof(int), stream);
  hipMemsetAsync(scnt, 0, (size_t)N * sizeof(int), stream);

  g_kernel<<<(N * 144 + 255) / 256, 256, 0, stream>>>(x_re, x_im, W_conv, phase, g2, N);
  count_kernel<<<(E + 255) / 256, 256, 0, stream>>>(edges, cnt, scnt, E);
  scan_dual_kernel<<<1, 1024, 0, stream>>>(cnt, offs, cur, scnt, soffs, scur, N);
  fill_kernel<<<(E + 255) / 256, 256, 0, stream>>>(edges, cur, scur, wxp_re, wxp_im,
                                                   ln_re, ln_im, src_l, wln,
                                                   selist, sdpos, E);
  conv_src_kernel<<<(N + 3) / 4, 256, 0, stream>>>(soffs, selist, sdpos, sten_re,
                                                   sten_im, g2, yebuf, N);
  ye_reduce_kernel<<<(N + 3) / 4, 256, 0, stream>>>(offs, yebuf, b_nl, y, N);
  hist_kernel<<<(N + 7) / 8, 256, 0, stream>>>(offs, src_l, wln, y, desc_g, N);
  mlp1_kernel<<<(N + 63) / 64, 256, 0, stream>>>(desc_g, W1, b1, h1_g, N);
  mlp23_kernel<<<(N + 63) / 64, 256, 0, stream>>>(h1_g, x_re, x_im, W2, b2,
                                                  W3, b3, Wres, bres, out, N);
}